// Round 1
// baseline (472.362 us; speedup 1.0000x reference)
//
#include <hip/hip_runtime.h>
#include <math.h>

// Problem constants (fixed by the reference): B=8, K=512, N=16384, D=128
constexpr int B = 8, K = 512, N = 16384, D = 128;

// ---------------------------------------------------------------------------
// Kernel 1: tgt_max[b*D+d] = max_n tgt_embedding[b,d,n]
// ---------------------------------------------------------------------------
__global__ __launch_bounds__(256) void k_tgt_max(const float* __restrict__ tgt,
                                                 float* __restrict__ tmax) {
    const int row = blockIdx.x;  // b*D + d
    const float4* src = (const float4*)(tgt + (size_t)row * N);
    float m = -INFINITY;
    for (int i = threadIdx.x; i < N / 4; i += 256) {
        float4 v = src[i];
        m = fmaxf(m, fmaxf(fmaxf(v.x, v.y), fmaxf(v.z, v.w)));
    }
    for (int off = 32; off; off >>= 1) m = fmaxf(m, __shfl_down(m, off));
    __shared__ float sm[4];
    if ((threadIdx.x & 63) == 0) sm[threadIdx.x >> 6] = m;
    __syncthreads();
    if (threadIdx.x == 0) {
        tmax[row] = fmaxf(fmaxf(sm[0], sm[1]), fmaxf(sm[2], sm[3]));
    }
}

// ---------------------------------------------------------------------------
// Kernel 2: bias[b] = sum_d tgt_max[b,d] * conv_w[D+d]
// ---------------------------------------------------------------------------
__global__ __launch_bounds__(128) void k_bias(const float* __restrict__ tmax,
                                              const float* __restrict__ conv_w,
                                              float* __restrict__ bias) {
    const int b = blockIdx.x;
    const int d = threadIdx.x;  // 0..127
    float v = tmax[b * D + d] * conv_w[D + d];
    for (int off = 32; off; off >>= 1) v += __shfl_down(v, off);
    __shared__ float sv[2];
    if ((d & 63) == 0) sv[d >> 6] = v;
    __syncthreads();
    if (d == 0) bias[b] = sv[0] + sv[1];
}

// ---------------------------------------------------------------------------
// Kernel 3: logits[b,n] = sum_d src[b,d,n]*conv_w[d] + bias[b]
// One thread per 4 columns (float4). grid = B*N/4/256 blocks.
// 16 blocks per batch (N/4/256 = 16) -> b uniform within a block.
// ---------------------------------------------------------------------------
__global__ __launch_bounds__(256) void k_logits(const float* __restrict__ src,
                                                const float* __restrict__ conv_w,
                                                const float* __restrict__ bias,
                                                float* __restrict__ logits) {
    const int gid = blockIdx.x * 256 + threadIdx.x;  // over B * N/4
    const int b = gid / (N / 4);
    const int c4 = gid % (N / 4);
    const float4* sp = (const float4*)(src + (size_t)b * D * N) + c4;
    float4 acc = {0.f, 0.f, 0.f, 0.f};
#pragma unroll 4
    for (int d = 0; d < D; ++d) {
        const float w = conv_w[d];
        float4 v = sp[(size_t)d * (N / 4)];
        acc.x = fmaf(v.x, w, acc.x);
        acc.y = fmaf(v.y, w, acc.y);
        acc.z = fmaf(v.z, w, acc.z);
        acc.w = fmaf(v.w, w, acc.w);
    }
    const float bb = bias[b];
    acc.x += bb; acc.y += bb; acc.z += bb; acc.w += bb;
    ((float4*)logits)[gid] = acc;
}

// ---------------------------------------------------------------------------
// Kernel 4: idx[b*K+k] = argmax_n (logits[b,n] + gumbel(b,k,n)) * sign(tau)
// One 256-thread block per (b,k). First-occurrence tie-break like jnp.argmax.
// ---------------------------------------------------------------------------
__device__ __forceinline__ void amax_update(float v, int n, float& best, int& bi) {
    // strict > keeps the earliest index within a thread's increasing-n scan
    if (v > best) { best = v; bi = n; }
}

__global__ __launch_bounds__(256) void k_argmax(const float* __restrict__ gum,
                                                const float* __restrict__ logits,
                                                const float* __restrict__ temp,
                                                int* __restrict__ idx_out) {
    const int b = blockIdx.x / K;
    const int k = blockIdx.x % K;
    const float4* gp = (const float4*)(gum + ((size_t)b * K + k) * N);
    const float4* lp = (const float4*)(logits + (size_t)b * N);
    const float sgn = (temp[b] < 0.f) ? -1.f : 1.f;

    float best = -INFINITY;
    int bi = 0;
    for (int i = threadIdx.x; i < N / 4; i += 256) {
        const float4 g4 = gp[i];
        const float4 l4 = lp[i];
        const int n0 = i * 4;
        {
            float u = fminf(fmaxf(g4.x, 1e-10f), 1.0f);
            float g = -logf(-logf(u));
            amax_update((l4.x + g) * sgn, n0 + 0, best, bi);
        }
        {
            float u = fminf(fmaxf(g4.y, 1e-10f), 1.0f);
            float g = -logf(-logf(u));
            amax_update((l4.y + g) * sgn, n0 + 1, best, bi);
        }
        {
            float u = fminf(fmaxf(g4.z, 1e-10f), 1.0f);
            float g = -logf(-logf(u));
            amax_update((l4.z + g) * sgn, n0 + 2, best, bi);
        }
        {
            float u = fminf(fmaxf(g4.w, 1e-10f), 1.0f);
            float g = -logf(-logf(u));
            amax_update((l4.w + g) * sgn, n0 + 3, best, bi);
        }
    }

    // wave reduce (64 lanes), index tie-break -> lower n
    for (int off = 32; off; off >>= 1) {
        float ov = __shfl_down(best, off);
        int oi = __shfl_down(bi, off);
        if (ov > best || (ov == best && oi < bi)) { best = ov; bi = oi; }
    }
    __shared__ float sv[4];
    __shared__ int si[4];
    if ((threadIdx.x & 63) == 0) {
        sv[threadIdx.x >> 6] = best;
        si[threadIdx.x >> 6] = bi;
    }
    __syncthreads();
    if (threadIdx.x == 0) {
#pragma unroll
        for (int j = 1; j < 4; ++j) {
            if (sv[j] > best || (sv[j] == best && si[j] < bi)) { best = sv[j]; bi = si[j]; }
        }
        idx_out[blockIdx.x] = bi;
    }
}

// ---------------------------------------------------------------------------
// Kernel 5: gather
//   out[0 : B*3*K]              = new_points  (b,c,k)
//   out[B*3*K : B*3*K + B*D*K]  = new_embedding (b,d,k)
// grid (B, 3+D), block K=512; coalesced writes over k.
// ---------------------------------------------------------------------------
__global__ __launch_bounds__(512) void k_gather(const float* __restrict__ points,
                                                const float* __restrict__ src,
                                                const int* __restrict__ idx,
                                                float* __restrict__ out) {
    const int b = blockIdx.x;
    const int row = blockIdx.y;  // 0..2 = points channel, 3.. = embedding dim
    const int k = threadIdx.x;
    const int id = idx[b * K + k];
    if (row < 3) {
        const float v = points[((size_t)b * 3 + row) * N + id];
        out[((size_t)b * 3 + row) * K + k] = v;
    } else {
        const int d = row - 3;
        const float v = src[((size_t)b * D + d) * N + id];
        out[(size_t)B * 3 * K + ((size_t)b * D + d) * K + k] = v;
    }
}

// ---------------------------------------------------------------------------
extern "C" void kernel_launch(void* const* d_in, const int* in_sizes, int n_in,
                              void* d_out, int out_size, void* d_ws, size_t ws_size,
                              hipStream_t stream) {
    const float* points = (const float*)d_in[0];  // (B,3,N)
    const float* src    = (const float*)d_in[1];  // (B,D,N)
    const float* tgt    = (const float*)d_in[2];  // (B,D,N)
    const float* temp   = (const float*)d_in[3];  // (B,)
    const float* conv_w = (const float*)d_in[4];  // (2D,)
    const float* gum    = (const float*)d_in[5];  // (B,K,N)
    float* out = (float*)d_out;

    // ws layout (floats): [0,1024) tgt_max | [1024,1032) bias |
    //                     [1040, 1040+B*N) logits (16B aligned) | then idx ints
    float* ws = (float*)d_ws;
    float* tmax = ws;
    float* bias = ws + B * D;
    float* logits = ws + 1040;
    int* idxb = (int*)(ws + 1040 + (size_t)B * N);

    k_tgt_max<<<B * D, 256, 0, stream>>>(tgt, tmax);
    k_bias<<<B, 128, 0, stream>>>(tmax, conv_w, bias);
    k_logits<<<(B * N / 4) / 256, 256, 0, stream>>>(src, conv_w, bias, logits);
    k_argmax<<<B * K, 256, 0, stream>>>(gum, logits, temp, idxb);
    k_gather<<<dim3(B, 3 + D), K, 0, stream>>>(points, src, idxb, out);
}

// Round 2
// 440.743 us; speedup vs baseline: 1.0717x; 1.0717x over previous
//
#include <hip/hip_runtime.h>
#include <math.h>

// Problem constants (fixed by the reference): B=8, K=512, N=16384, D=128
constexpr int B = 8, K = 512, N = 16384, D = 128;

// ---------------------------------------------------------------------------
// Kernel 1: q[b,n] = sgn(tau_b) * exp( - sum_d src[b,d,n]*conv_w[d] )
//
// Math: argmax_n (logits+g)/tau  ==  argmin_n t*q  with t = -ln(u),
//       q = sgn * exp(-logits). The per-batch bias (tgt_global . w_tgt) is a
//       uniform shift of logits -> softmax/argmax invariant -> DROPPED
//       (tgt_embedding is unused). |tau| is a positive scale -> invariant.
//
// One thread per 2 columns (float2): B*N/2 = 64K threads = 256 blocks.
// ---------------------------------------------------------------------------
__global__ __launch_bounds__(256) void k_q(const float* __restrict__ src,
                                           const float* __restrict__ conv_w,
                                           const float* __restrict__ temp,
                                           float* __restrict__ q) {
    const int gid = blockIdx.x * 256 + threadIdx.x;  // over B * N/2
    const int b = gid / (N / 2);
    const int c2 = gid % (N / 2);
    const float2* sp = (const float2*)(src + (size_t)b * D * N) + c2;
    float ax = 0.f, ay = 0.f;
#pragma unroll 8
    for (int d = 0; d < D; ++d) {
        const float w = conv_w[d];
        float2 v = sp[(size_t)d * (N / 2)];
        ax = fmaf(v.x, w, ax);
        ay = fmaf(v.y, w, ay);
    }
    const float sgn = (temp[b] < 0.f) ? -1.f : 1.f;
    float2 o;
    o.x = sgn * expf(-ax);
    o.y = sgn * expf(-ay);
    ((float2*)q)[gid] = o;
}

// ---------------------------------------------------------------------------
// Kernel 2: idx[b*K+k] = argmin_n t(u[b,k,n]) * q[b,n]
//   t = -ln(u):  u near 1 (the only possible winners) -> exact series
//                t = w*(1 + w*(1/2 + w/3)), w = 1-u (Sterbenz-exact there);
//                else  t = -log2(u)*ln2 via v_log_f32 (never a contender,
//                P(max u < 0.992) ~ e^-131, so HW log error is harmless).
// First-occurrence tie-break (strict < in scan, lower-index in reductions).
// One 256-thread block per (b,k); 4096 blocks.
// ---------------------------------------------------------------------------
__device__ __forceinline__ float neg_ln(float u) {
    u = fmaxf(u, 1e-10f);                       // clip: (1 - 1e-10) rounds to 1.0f -> upper clip is a no-op
    const float w = 1.0f - u;
    const float tf = __builtin_amdgcn_logf(u) * -0.69314718056f;  // -log2(u)*ln2
    const float tp = w * fmaf(w, fmaf(w, 0.33333334f, 0.5f), 1.0f);
    return (w < 0.0078125f) ? tp : tf;
}

__device__ __forceinline__ void amin_update(float v, int n, float& best, int& bi) {
    if (v < best) { best = v; bi = n; }
}

__global__ __launch_bounds__(256) void k_argmin(const float* __restrict__ gum,
                                                const float* __restrict__ q,
                                                int* __restrict__ idx_out) {
    const int b = blockIdx.x / K;
    const float4* gp = (const float4*)(gum + (size_t)blockIdx.x * N);
    const float4* qp = (const float4*)(q + (size_t)b * N);

    float best = INFINITY;
    int bi = 0;
    for (int i = threadIdx.x; i < N / 4; i += 256) {
        const float4 g4 = gp[i];
        const float4 q4 = qp[i];
        const int n0 = i * 4;
        amin_update(neg_ln(g4.x) * q4.x, n0 + 0, best, bi);
        amin_update(neg_ln(g4.y) * q4.y, n0 + 1, best, bi);
        amin_update(neg_ln(g4.z) * q4.z, n0 + 2, best, bi);
        amin_update(neg_ln(g4.w) * q4.w, n0 + 3, best, bi);
    }

    // wave reduce (64 lanes), tie -> lower n
    for (int off = 32; off; off >>= 1) {
        float ov = __shfl_down(best, off);
        int oi = __shfl_down(bi, off);
        if (ov < best || (ov == best && oi < bi)) { best = ov; bi = oi; }
    }
    __shared__ float sv[4];
    __shared__ int si[4];
    if ((threadIdx.x & 63) == 0) {
        sv[threadIdx.x >> 6] = best;
        si[threadIdx.x >> 6] = bi;
    }
    __syncthreads();
    if (threadIdx.x == 0) {
#pragma unroll
        for (int j = 1; j < 4; ++j) {
            if (sv[j] < best || (sv[j] == best && si[j] < bi)) { best = sv[j]; bi = si[j]; }
        }
        idx_out[blockIdx.x] = bi;
    }
}

// ---------------------------------------------------------------------------
// Kernel 3: gather
//   out[0 : B*3*K]              = new_points    (b,c,k) = points[b,c,idx]
//   out[B*3*K : B*3*K + B*D*K]  = new_embedding (b,d,k) = src[b,d,idx]
// (scores are exactly one-hot in IEEE: off-argmax (0-y)+y == +0, argmax
//  fl(fl(1-y)+y) == 1 within 1 ulp -- r1 measured absmax 0.0)
// grid (B, 3+D), block K=512; coalesced writes over k.
// ---------------------------------------------------------------------------
__global__ __launch_bounds__(512) void k_gather(const float* __restrict__ points,
                                                const float* __restrict__ src,
                                                const int* __restrict__ idx,
                                                float* __restrict__ out) {
    const int b = blockIdx.x;
    const int row = blockIdx.y;  // 0..2 = points channel, 3.. = embedding dim
    const int k = threadIdx.x;
    const int id = idx[b * K + k];
    if (row < 3) {
        out[((size_t)b * 3 + row) * K + k] = points[((size_t)b * 3 + row) * N + id];
    } else {
        const int d = row - 3;
        out[(size_t)B * 3 * K + ((size_t)b * D + d) * K + k] =
            src[((size_t)b * D + d) * N + id];
    }
}

// ---------------------------------------------------------------------------
extern "C" void kernel_launch(void* const* d_in, const int* in_sizes, int n_in,
                              void* d_out, int out_size, void* d_ws, size_t ws_size,
                              hipStream_t stream) {
    const float* points = (const float*)d_in[0];  // (B,3,N)
    const float* src    = (const float*)d_in[1];  // (B,D,N)
    // d_in[2] = tgt_embedding : provably unused (uniform logit shift)
    const float* temp   = (const float*)d_in[3];  // (B,)
    const float* conv_w = (const float*)d_in[4];  // (2D,) -- only first D used
    const float* gum    = (const float*)d_in[5];  // (B,K,N)
    float* out = (float*)d_out;

    // ws layout (floats): [0, B*N) q | then B*K ints idx
    float* ws = (float*)d_ws;
    float* q = ws;
    int* idxb = (int*)(ws + (size_t)B * N);

    k_q<<<(B * N / 2) / 256, 256, 0, stream>>>(src, conv_w, temp, q);
    k_argmin<<<B * K, 256, 0, stream>>>(gum, q, idxb);
    k_gather<<<dim3(B, 3 + D), K, 0, stream>>>(points, src, idxb, out);
}